// Round 4
// baseline (8794.782 us; speedup 1.0000x reference)
//
#include <hip/hip_runtime.h>
#include <math.h>

#define B_ 32
#define N_ 1023
#define E_ 256
#define H_ 512
#define V_ 32000
#define T_ 64
#define NBL 250   // logits blocks (128 cols each)
#define DECB 256  // decoder persistent blocks

__device__ __forceinline__ float sigf(float x) { return 1.0f / (1.0f + expf(-x)); }

// ---------------------------------------------------------------------------
// grid barrier: one-shot counter per barrier instance (memset to 0 each call)
// ---------------------------------------------------------------------------
__device__ __forceinline__ void gridbar(unsigned* c)
{
    __syncthreads();
    if (threadIdx.x == 0) {
        __threadfence();
        __hip_atomic_fetch_add(c, 1u, __ATOMIC_ACQ_REL, __HIP_MEMORY_SCOPE_AGENT);
        while (__hip_atomic_load(c, __ATOMIC_ACQUIRE, __HIP_MEMORY_SCOPE_AGENT) < (unsigned)DECB) {
            __builtin_amdgcn_s_sleep(2);
        }
        __threadfence();
    }
    __syncthreads();
}

// ---------------------------------------------------------------------------
// Tree iou GEMM (large levels): 128x128 tile, 8x8 micro.
// ---------------------------------------------------------------------------
template<bool LEAF>
__global__ void __launch_bounds__(256)
iou_gemm_k(const int* __restrict__ node_feat, const int* __restrict__ mask,
           const float* __restrict__ emb, const float* __restrict__ Wiou,
           const float* __restrict__ Uiou, const float* __restrict__ hbuf,
           float* __restrict__ iou_out, int first, int n, int nshift)
{
    const int rows = B_ * n;
    const int K = LEAF ? E_ : (E_ + H_);
    const int rt = blockIdx.x, ct = blockIdx.y;
    const int tid = threadIdx.x;
    const int tr = tid >> 4, tc = tid & 15;

    __shared__ __align__(16) float As[8][136];
    __shared__ __align__(16) float Bs[8][136];

    float acc[8][8];
#pragma unroll
    for (int i = 0; i < 8; ++i)
#pragma unroll
        for (int j = 0; j < 8; ++j) acc[i][j] = 0.0f;

    const int lrow = tid >> 1;
    const int lkq  = (tid & 1) << 2;
    const int grow = rt * 128 + lrow;
    const bool rvalid = grow < rows;
    int tok = 0; float mval = 0.0f; int hoff1 = 0, hoff2 = 0;
    if (rvalid) {
        const int b = grow >> nshift, j = grow & (n - 1);
        const int node = first + j;
        tok  = node_feat[b * N_ + node];
        mval = (float)mask[b * N_ + node];
        if (!LEAF) {
            hoff1 = (b * N_ + 2 * node + 1) * H_;
            hoff2 = hoff1 + H_;
        }
    }
    const int bk   = tid >> 5;
    const int bcol = (tid & 31) << 2;
    const int gcol = ct * 128 + bcol;

    const int nkt = K >> 3;
    for (int kt = 0; kt < nkt; ++kt) {
        const int k0 = kt << 3;
        {
            const int kg = k0 + lkq;
            float4 v = make_float4(0.f, 0.f, 0.f, 0.f);
            if (rvalid) {
                if (LEAF || kg < E_) {
                    float4 e = *(const float4*)(emb + tok * E_ + kg);
                    v.x = e.x * mval; v.y = e.y * mval; v.z = e.z * mval; v.w = e.w * mval;
                } else {
                    const int kk = kg - E_;
                    float4 h1 = *(const float4*)(hbuf + hoff1 + kk);
                    float4 h2 = *(const float4*)(hbuf + hoff2 + kk);
                    v.x = h1.x + h2.x; v.y = h1.y + h2.y;
                    v.z = h1.z + h2.z; v.w = h1.w + h2.w;
                }
            }
            As[lkq + 0][lrow] = v.x;
            As[lkq + 1][lrow] = v.y;
            As[lkq + 2][lrow] = v.z;
            As[lkq + 3][lrow] = v.w;
        }
        {
            const int kg = k0 + bk;
            const float* src = (LEAF || kg < E_) ? (Wiou + kg * 1536 + gcol)
                                                 : (Uiou + (kg - E_) * 1536 + gcol);
            *(float4*)&Bs[bk][bcol] = *(const float4*)src;
        }
        __syncthreads();
#pragma unroll
        for (int kk = 0; kk < 8; ++kk) {
            float a[8], bb[8];
            *(float4*)&a[0]  = *(const float4*)&As[kk][tr << 3];
            *(float4*)&a[4]  = *(const float4*)&As[kk][(tr << 3) + 4];
            *(float4*)&bb[0] = *(const float4*)&Bs[kk][tc << 2];
            *(float4*)&bb[4] = *(const float4*)&Bs[kk][(tc << 2) + 64];
#pragma unroll
            for (int i = 0; i < 8; ++i)
#pragma unroll
                for (int j = 0; j < 8; ++j)
                    acc[i][j] = fmaf(a[i], bb[j], acc[i][j]);
        }
        __syncthreads();
    }
#pragma unroll
    for (int i = 0; i < 8; ++i) {
        const int r = rt * 128 + (tr << 3) + i;
        if (r < rows) {
            float* dst = iou_out + (size_t)r * 1536 + ct * 128;
            *(float4*)(dst + (tc << 2))      = make_float4(acc[i][0], acc[i][1], acc[i][2], acc[i][3]);
            *(float4*)(dst + 64 + (tc << 2)) = make_float4(acc[i][4], acc[i][5], acc[i][6], acc[i][7]);
        }
    }
}

// ---------------------------------------------------------------------------
// Tree iou GEMM (small levels, n<=64): 64x64 tile, 4x4 micro. Internal only.
// ---------------------------------------------------------------------------
__global__ void __launch_bounds__(256)
iou_small_k(const int* __restrict__ node_feat, const int* __restrict__ mask,
            const float* __restrict__ emb, const float* __restrict__ Wiou,
            const float* __restrict__ Uiou, const float* __restrict__ hbuf,
            float* __restrict__ iou_out, int first, int n, int nshift)
{
    const int rows = B_ * n;
    const int rt = blockIdx.x, ct = blockIdx.y;   // ct: 24 tiles of 64 cols
    const int tid = threadIdx.x;
    const int tr = tid >> 4, tc = tid & 15;

    __shared__ __align__(16) float As[8][72];
    __shared__ __align__(16) float Bs[8][72];

    float acc[4][4];
#pragma unroll
    for (int i = 0; i < 4; ++i)
#pragma unroll
        for (int j = 0; j < 4; ++j) acc[i][j] = 0.0f;

    const int srow = tid & 63, skq = tid >> 6;    // stage row srow, k = skq*2+{0,1}
    const int grow = rt * 64 + srow;
    const bool rvalid = grow < rows;
    int tok = 0; float mval = 0.f; int hoff1 = 0, hoff2 = 0;
    if (rvalid) {
        const int b = grow >> nshift, j = grow & (n - 1);
        const int node = first + j;
        tok  = node_feat[b * N_ + node];
        mval = (float)mask[b * N_ + node];
        hoff1 = (b * N_ + 2 * node + 1) * H_;
        hoff2 = hoff1 + H_;
    }
    const int gcol = ct * 64 + srow;

    for (int kt = 0; kt < 96; ++kt) {
        const int k0 = kt << 3;
        {   // A (gathered, float2 per thread)
            const int kg = k0 + (skq << 1);
            float2 v = make_float2(0.f, 0.f);
            if (rvalid) {
                if (kg < E_) {
                    float2 e = *(const float2*)(emb + tok * E_ + kg);
                    v.x = e.x * mval; v.y = e.y * mval;
                } else {
                    const int kk = kg - E_;
                    float2 h1 = *(const float2*)(hbuf + hoff1 + kk);
                    float2 h2 = *(const float2*)(hbuf + hoff2 + kk);
                    v.x = h1.x + h2.x; v.y = h1.y + h2.y;
                }
            }
            As[(skq << 1) + 0][srow] = v.x;
            As[(skq << 1) + 1][srow] = v.y;
        }
        {   // B (2 scalar rows)
            const int kg = k0 + (skq << 1);
            const float* s0 = (kg < E_) ? (Wiou + (size_t)kg * 1536 + gcol)
                                        : (Uiou + (size_t)(kg - E_) * 1536 + gcol);
            const float* s1 = ((kg + 1) < E_) ? (Wiou + (size_t)(kg + 1) * 1536 + gcol)
                                              : (Uiou + (size_t)(kg + 1 - E_) * 1536 + gcol);
            Bs[(skq << 1) + 0][srow] = *s0;
            Bs[(skq << 1) + 1][srow] = *s1;
        }
        __syncthreads();
#pragma unroll
        for (int kk = 0; kk < 8; ++kk) {
            float a[4], bb[4];
            *(float4*)&a[0]  = *(const float4*)&As[kk][tr << 2];
            *(float4*)&bb[0] = *(const float4*)&Bs[kk][tc << 2];
#pragma unroll
            for (int i = 0; i < 4; ++i)
#pragma unroll
                for (int j = 0; j < 4; ++j)
                    acc[i][j] = fmaf(a[i], bb[j], acc[i][j]);
        }
        __syncthreads();
    }
#pragma unroll
    for (int i = 0; i < 4; ++i) {
        const int r = rt * 64 + (tr << 2) + i;
        if (r < rows)
            *(float4*)(iou_out + (size_t)r * 1536 + ct * 64 + (tc << 2)) =
                make_float4(acc[i][0], acc[i][1], acc[i][2], acc[i][3]);
    }
}

// ---------------------------------------------------------------------------
// f-gate GEMM (large levels): 128x128 tile with fused c_agg epilogue.
// ---------------------------------------------------------------------------
__global__ void __launch_bounds__(256)
fagg_gemm_k(const float* __restrict__ hbuf, const float* __restrict__ cbuf,
            const float* __restrict__ Ufw, const float* __restrict__ Ufb,
            float* __restrict__ cagg, int first, int n, int nshift)
{
    const int rows = 64 * n;
    const int rt = blockIdx.x, ct = blockIdx.y;
    const int tid = threadIdx.x;
    const int tr = tid >> 4, tc = tid & 15;

    __shared__ __align__(16) float As[8][136];
    __shared__ __align__(16) float Bs[8][136];

    float acc[8][8];
#pragma unroll
    for (int i = 0; i < 8; ++i)
#pragma unroll
        for (int j = 0; j < 8; ++j) acc[i][j] = 0.0f;

    const int lrow = tid >> 1;
    const int lkq  = (tid & 1) << 2;
    const int grow = rt * 128 + lrow;
    const bool rvalid = grow < rows;
    int hoff = 0;
    if (rvalid) {
        const int bj = grow >> 1, s = grow & 1;
        const int b = bj >> nshift, j = bj & (n - 1);
        const int node = first + j;
        hoff = (b * N_ + 2 * node + 1 + s) * H_;
    }
    const int bk   = tid >> 5;
    const int bcol = (tid & 31) << 2;
    const int gcol = ct * 128 + bcol;

    for (int kt = 0; kt < 64; ++kt) {
        const int k0 = kt << 3;
        {
            const int kg = k0 + lkq;
            float4 v = make_float4(0.f, 0.f, 0.f, 0.f);
            if (rvalid) v = *(const float4*)(hbuf + hoff + kg);
            As[lkq + 0][lrow] = v.x;
            As[lkq + 1][lrow] = v.y;
            As[lkq + 2][lrow] = v.z;
            As[lkq + 3][lrow] = v.w;
        }
        {
            const int kg = k0 + bk;
            *(float4*)&Bs[bk][bcol] = *(const float4*)(Ufw + kg * H_ + gcol);
        }
        __syncthreads();
#pragma unroll
        for (int kk = 0; kk < 8; ++kk) {
            float a[8], bb[8];
            *(float4*)&a[0]  = *(const float4*)&As[kk][tr << 3];
            *(float4*)&a[4]  = *(const float4*)&As[kk][(tr << 3) + 4];
            *(float4*)&bb[0] = *(const float4*)&Bs[kk][tc << 2];
            *(float4*)&bb[4] = *(const float4*)&Bs[kk][(tc << 2) + 64];
#pragma unroll
            for (int i = 0; i < 8; ++i)
#pragma unroll
                for (int j = 0; j < 8; ++j)
                    acc[i][j] = fmaf(a[i], bb[j], acc[i][j]);
        }
        __syncthreads();
    }
#pragma unroll
    for (int p = 0; p < 4; ++p) {
        const int r0 = rt * 128 + (tr << 3) + 2 * p;
        if (r0 < rows) {
            const int bj = r0 >> 1;
            const int b = bj >> nshift, j = bj & (n - 1);
            const int node = first + j;
            const float* c1 = cbuf + (b * N_ + 2 * node + 1) * H_ + ct * 128;
            const float* c2 = c1 + H_;
            float* dst = cagg + bj * H_ + ct * 128;
#pragma unroll
            for (int g = 0; g < 2; ++g) {
                const int off = (g ? 64 : 0) + (tc << 2);
                const int jb = g * 4;
                float4 cc1 = *(const float4*)(c1 + off);
                float4 cc2 = *(const float4*)(c2 + off);
                float4 bbv = *(const float4*)(Ufb + ct * 128 + off);
                float4 res;
                res.x = sigf(acc[2*p][jb+0] + bbv.x) * cc1.x + sigf(acc[2*p+1][jb+0] + bbv.x) * cc2.x;
                res.y = sigf(acc[2*p][jb+1] + bbv.y) * cc1.y + sigf(acc[2*p+1][jb+1] + bbv.y) * cc2.y;
                res.z = sigf(acc[2*p][jb+2] + bbv.z) * cc1.z + sigf(acc[2*p+1][jb+2] + bbv.z) * cc2.z;
                res.w = sigf(acc[2*p][jb+3] + bbv.w) * cc1.w + sigf(acc[2*p+1][jb+3] + bbv.w) * cc2.w;
                *(float4*)(dst + off) = res;
            }
        }
    }
}

// ---------------------------------------------------------------------------
// f-gate GEMM (small levels, n<=64): 64x64 tile, 4x4 micro, fused epilogue.
// ---------------------------------------------------------------------------
__global__ void __launch_bounds__(256)
fagg_small_k(const float* __restrict__ hbuf, const float* __restrict__ cbuf,
             const float* __restrict__ Ufw, const float* __restrict__ Ufb,
             float* __restrict__ cagg, int first, int n, int nshift)
{
    const int rows = 64 * n;
    const int rt = blockIdx.x, ct = blockIdx.y;   // ct: 8 tiles of 64 cols
    const int tid = threadIdx.x;
    const int tr = tid >> 4, tc = tid & 15;

    __shared__ __align__(16) float As[8][72];
    __shared__ __align__(16) float Bs[8][72];

    float acc[4][4];
#pragma unroll
    for (int i = 0; i < 4; ++i)
#pragma unroll
        for (int j = 0; j < 4; ++j) acc[i][j] = 0.0f;

    const int srow = tid & 63, skq = tid >> 6;
    const int grow = rt * 64 + srow;
    const bool rvalid = grow < rows;
    int hoff = 0;
    if (rvalid) {
        const int bj = grow >> 1, s = grow & 1;
        const int b = bj >> nshift, j = bj & (n - 1);
        const int node = first + j;
        hoff = (b * N_ + 2 * node + 1 + s) * H_;
    }
    const int gcol = ct * 64 + srow;

    for (int kt = 0; kt < 64; ++kt) {
        const int k0 = kt << 3;
        {
            const int kg = k0 + (skq << 1);
            float2 v = make_float2(0.f, 0.f);
            if (rvalid) v = *(const float2*)(hbuf + hoff + kg);
            As[(skq << 1) + 0][srow] = v.x;
            As[(skq << 1) + 1][srow] = v.y;
        }
        {
            const int kg = k0 + (skq << 1);
            Bs[(skq << 1) + 0][srow] = Ufw[(size_t)kg * H_ + gcol];
            Bs[(skq << 1) + 1][srow] = Ufw[(size_t)(kg + 1) * H_ + gcol];
        }
        __syncthreads();
#pragma unroll
        for (int kk = 0; kk < 8; ++kk) {
            float a[4], bb[4];
            *(float4*)&a[0]  = *(const float4*)&As[kk][tr << 2];
            *(float4*)&bb[0] = *(const float4*)&Bs[kk][tc << 2];
#pragma unroll
            for (int i = 0; i < 4; ++i)
#pragma unroll
                for (int j = 0; j < 4; ++j)
                    acc[i][j] = fmaf(a[i], bb[j], acc[i][j]);
        }
        __syncthreads();
    }
#pragma unroll
    for (int p = 0; p < 2; ++p) {
        const int r0 = rt * 64 + (tr << 2) + 2 * p;
        if (r0 < rows) {
            const int bj = r0 >> 1;
            const int b = bj >> nshift, j = bj & (n - 1);
            const int node = first + j;
            const float* c1 = cbuf + (b * N_ + 2 * node + 1) * H_ + ct * 64;
            const float* c2 = c1 + H_;
            float* dst = cagg + bj * H_ + ct * 64;
            const int off = tc << 2;
            float4 cc1 = *(const float4*)(c1 + off);
            float4 cc2 = *(const float4*)(c2 + off);
            float4 bbv = *(const float4*)(Ufb + ct * 64 + off);
            float4 res;
            res.x = sigf(acc[2*p][0] + bbv.x) * cc1.x + sigf(acc[2*p+1][0] + bbv.x) * cc2.x;
            res.y = sigf(acc[2*p][1] + bbv.y) * cc1.y + sigf(acc[2*p+1][1] + bbv.y) * cc2.y;
            res.z = sigf(acc[2*p][2] + bbv.z) * cc1.z + sigf(acc[2*p+1][2] + bbv.z) * cc2.z;
            res.w = sigf(acc[2*p][3] + bbv.w) * cc1.w + sigf(acc[2*p+1][3] + bbv.w) * cc2.w;
            *(float4*)(dst + off) = res;
        }
    }
}

// ---------------------------------------------------------------------------
template<bool LEAF>
__global__ void apply_node_k(const float* __restrict__ iou,
                             const float* __restrict__ b_iou,
                             const float* __restrict__ cagg,
                             float* __restrict__ hbuf, float* __restrict__ cbuf,
                             int first, int n, int nshift)
{
    const int gid = blockIdx.x * 256 + threadIdx.x;
    if (gid >= B_ * n * 128) return;
    const int r = gid >> 7, col = (gid & 127) << 2;
    const float* row = iou + (size_t)r * 1536;
    float4 iv = *(const float4*)(row + col);
    float4 ov = *(const float4*)(row + 512 + col);
    float4 uv = *(const float4*)(row + 1024 + col);
    float4 bi = *(const float4*)(b_iou + col);
    float4 bo = *(const float4*)(b_iou + 512 + col);
    float4 bu = *(const float4*)(b_iou + 1024 + col);
    float4 ca = make_float4(0.f, 0.f, 0.f, 0.f);
    if (!LEAF) ca = *(const float4*)(cagg + r * H_ + col);
    float4 cn, hn;
    cn.x = sigf(iv.x + bi.x) * tanhf(uv.x + bu.x) + ca.x;
    cn.y = sigf(iv.y + bi.y) * tanhf(uv.y + bu.y) + ca.y;
    cn.z = sigf(iv.z + bi.z) * tanhf(uv.z + bu.z) + ca.z;
    cn.w = sigf(iv.w + bi.w) * tanhf(uv.w + bu.w) + ca.w;
    hn.x = sigf(ov.x + bo.x) * tanhf(cn.x);
    hn.y = sigf(ov.y + bo.y) * tanhf(cn.y);
    hn.z = sigf(ov.z + bo.z) * tanhf(cn.z);
    hn.w = sigf(ov.w + bo.w) * tanhf(cn.w);
    const int b = r >> nshift, j = r & (n - 1);
    const int node = first + j;
    const size_t o = (size_t)(b * N_ + node) * H_ + col;
    *(float4*)(cbuf + o) = cn;
    *(float4*)(hbuf + o) = hn;
}

// ---------------------------------------------------------------------------
// two-stage mean over nodes
// ---------------------------------------------------------------------------
__global__ void mean_part_k(const float* __restrict__ hbuf, float* __restrict__ mpart)
{
    const int bid = blockIdx.x;               // 256 = 32 b x 8 chunks
    const int b = bid >> 3, chunk = bid & 7;
    const int tid = threadIdx.x;
    const int n0 = chunk * 128;
    const int n1 = (n0 + 128 < N_) ? (n0 + 128) : N_;
    float s0 = 0.f, s1 = 0.f;
    for (int nn = n0; nn < n1; ++nn) {
        const float* p = hbuf + (size_t)(b * N_ + nn) * H_;
        s0 += p[tid];
        s1 += p[tid + 256];
    }
    mpart[(bid << 9) + tid]       = s0;
    mpart[(bid << 9) + tid + 256] = s1;
}

__global__ void mean_fin_k(const float* __restrict__ mpart, float* __restrict__ mf)
{
    const int gid = blockIdx.x * 256 + threadIdx.x;   // 16384
    const int b = gid >> 9, k = gid & 511;
    float s = 0.f;
#pragma unroll
    for (int c = 0; c < 8; ++c) s += mpart[(((b << 3) + c) << 9) + k];
    mf[gid] = s * (1.0f / 1023.0f);
}

__global__ void hidcel_k(const float* __restrict__ mf,
                         const float* __restrict__ hw, const float* __restrict__ hb,
                         const float* __restrict__ cw, const float* __restrict__ cb,
                         float* __restrict__ hs0, float* __restrict__ cs)
{
    const int gid = blockIdx.x * 256 + threadIdx.x;   // 32768
    const int which = gid >> 14;
    const int b = (gid >> 9) & 31, l = gid & 511;
    const float* W = which ? cw : hw;
    float acc = which ? cb[l] : hb[l];
#pragma unroll 8
    for (int k = 0; k < H_; ++k) acc = fmaf(mf[b * H_ + k], W[k * H_ + l], acc);
    if (which) cs[b * H_ + l] = acc; else hs0[b * H_ + l] = acc;
}

// ---------------------------------------------------------------------------
// persistent decoder: 256 blocks (1/CU), 63 steps, 2 grid barriers per step.
// phase A (all blocks): argmax finalize -> token -> gates -> hs,cs (2 l-cols/block)
// phase B (blocks 0..249): logits GEMM 128 cols/block + argmax partials
// ---------------------------------------------------------------------------
__global__ void __launch_bounds__(256)
decoder_k(const float* __restrict__ emb, const float* __restrict__ W_ih,
          const float* __restrict__ W_hh, const float* __restrict__ b_ih,
          const float* __restrict__ b_hh, const float* __restrict__ fc_w,
          const float* __restrict__ fc_b, float* __restrict__ hsb,
          float* __restrict__ csb, float* __restrict__ out,
          float* __restrict__ pval, int* __restrict__ pidx, unsigned* bar)
{
    __shared__ __align__(16) float sh[24576];   // 96 KB union (xh / smem / partials)
    __shared__ float rv[256];
    __shared__ int   ri[256];
    __shared__ int   tokS[B_];
    const int bid = blockIdx.x, tid = threadIdx.x;

    for (int t = 1; t < T_; ++t) {
        const float* hs_in  = hsb + ((t - 1) & 1) * (B_ * H_);
        float*       hs_out = hsb + (t & 1) * (B_ * H_);

        // ================= phase A: lstm step =================
        if (t == 1) {
            if (tid < B_) tokS[tid] = 0;
        } else {
            const int b = tid & 31, ch = tid >> 5;
            float bv = -INFINITY; int bi2 = 0x7fffffff;
            for (int p = ch; p < NBL; p += 8) {
                const float v = pval[b * NBL + p];
                const int  ix = pidx[b * NBL + p];
                if (v > bv || (v == bv && ix < bi2)) { bv = v; bi2 = ix; }
            }
            rv[tid] = bv; ri[tid] = bi2;
            __syncthreads();
            if (tid < B_) {
                float Bv = -INFINITY; int Bi = 0x7fffffff;
#pragma unroll
                for (int c2 = 0; c2 < 8; ++c2) {
                    const float v = rv[c2 * 32 + tid];
                    const int  ix = ri[c2 * 32 + tid];
                    if (v > Bv || (v == Bv && ix < Bi)) { Bv = v; Bi = ix; }
                }
                tokS[tid] = Bi;
            }
        }
        __syncthreads();

        for (int idx = tid; idx < B_ * E_; idx += 256) {
            const int b = idx >> 8, k = idx & 255;
            sh[k * 32 + b] = emb[tokS[b] * E_ + k];
        }
        for (int idx = tid; idx < B_ * H_; idx += 256) {
            const int b = idx >> 9, k = idx & 511;
            sh[(E_ + k) * 32 + b] = hs_in[b * H_ + k];
        }
        __syncthreads();

        {
            const int b  = tid & 31;
            const int li = (tid >> 5) & 1;
            const int kq = tid >> 6;
            const int l  = bid * 2 + li;
            float ai = 0.f, af = 0.f, ag = 0.f, ao = 0.f;
            {
                const float* w  = W_ih + (kq * 64) * 2048 + l;
                const float* xp = sh + (kq * 64) * 32 + b;
#pragma unroll 8
                for (int k = 0; k < 64; ++k) {
                    const float x = xp[k * 32];
                    ai = fmaf(x, w[0],    ai);
                    af = fmaf(x, w[512],  af);
                    ag = fmaf(x, w[1024], ag);
                    ao = fmaf(x, w[1536], ao);
                    w += 2048;
                }
            }
            {
                const float* w  = W_hh + (kq * 128) * 2048 + l;
                const float* xp = sh + (E_ + kq * 128) * 32 + b;
#pragma unroll 8
                for (int k = 0; k < 128; ++k) {
                    const float x = xp[k * 32];
                    ai = fmaf(x, w[0],    ai);
                    af = fmaf(x, w[512],  af);
                    ag = fmaf(x, w[1024], ag);
                    ao = fmaf(x, w[1536], ao);
                    w += 2048;
                }
            }
            __syncthreads();       // xh reads done; reuse for partials
            {
                const int slot = ((kq * 2 + li) * 32 + b) * 4;
                sh[slot + 0] = ai; sh[slot + 1] = af;
                sh[slot + 2] = ag; sh[slot + 3] = ao;
            }
            __syncthreads();
            if (tid < 64) {
                const int b2 = tid & 31, li2 = tid >> 5;
                const int l2 = bid * 2 + li2;
                float s0 = 0.f, s1 = 0.f, s2 = 0.f, s3 = 0.f;
#pragma unroll
                for (int q = 0; q < 4; ++q) {
                    const int sl = ((q * 2 + li2) * 32 + b2) * 4;
                    s0 += sh[sl + 0]; s1 += sh[sl + 1];
                    s2 += sh[sl + 2]; s3 += sh[sl + 3];
                }
                const float gi = s0 + b_ih[l2]        + b_hh[l2];
                const float gf = s1 + b_ih[512 + l2]  + b_hh[512 + l2];
                const float gg = s2 + b_ih[1024 + l2] + b_hh[1024 + l2];
                const float go = s3 + b_ih[1536 + l2] + b_hh[1536 + l2];
                const float co = csb[b2 * H_ + l2];
                const float cn = sigf(gf) * co + sigf(gi) * tanhf(gg);
                csb[b2 * H_ + l2] = cn;
                hs_out[b2 * H_ + l2] = sigf(go) * tanhf(cn);
            }
        }
        gridbar(bar + 2 * t - 2);

        // ================= phase B: logits =================
        if (bid < NBL) {
            for (int idx = tid; idx < B_ * H_; idx += 256) {
                const int b = idx >> 9, k = idx & 511;
                sh[k * 36 + b] = hs_out[b * H_ + k];
            }
            __syncthreads();

            const int kq = tid >> 6, lane = tid & 63;
            const int col = lane << 1;
            float acc[32][2];
#pragma unroll
            for (int bb = 0; bb < 32; ++bb) { acc[bb][0] = 0.f; acc[bb][1] = 0.f; }

            const float* wp = fc_w + (size_t)(kq * 128) * V_ + bid * 128 + col;
            const float* hp = sh + (kq * 128) * 36;
            float2 wreg[8];
#pragma unroll
            for (int j = 0; j < 8; ++j) wreg[j] = *(const float2*)(wp + (size_t)j * V_);
            for (int kb = 0; kb < 16; ++kb) {
                float2 wnxt[8];
                if (kb < 15) {
                    const float* wq = wp + (size_t)((kb + 1) << 3) * V_;
#pragma unroll
                    for (int j = 0; j < 8; ++j) wnxt[j] = *(const float2*)(wq + (size_t)j * V_);
                }
#pragma unroll
                for (int j = 0; j < 8; ++j) {
                    const float* hq = hp + ((kb << 3) + j) * 36;
                    float hv[32];
#pragma unroll
                    for (int q = 0; q < 8; ++q)
                        *(float4*)&hv[q << 2] = *(const float4*)(hq + (q << 2));
#pragma unroll
                    for (int bb = 0; bb < 32; ++bb) {
                        acc[bb][0] = fmaf(hv[bb], wreg[j].x, acc[bb][0]);
                        acc[bb][1] = fmaf(hv[bb], wreg[j].y, acc[bb][1]);
                    }
                }
                if (kb < 15) {
#pragma unroll
                    for (int j = 0; j < 8; ++j) wreg[j] = wnxt[j];
                }
            }
            __syncthreads();      // hs reads done; reuse sh for partials

            float* redS = sh;     // [kq][b][132]
#pragma unroll
            for (int bb = 0; bb < 32; ++bb) {
                redS[kq * 4224 + bb * 132 + col]     = acc[bb][0];
                redS[kq * 4224 + bb * 132 + col + 1] = acc[bb][1];
            }
            __syncthreads();

            float* out_t = out + (size_t)t * (B_ * V_);
            for (int idx = tid; idx < 4096; idx += 256) {
                const int c2 = idx & 127, b = idx >> 7;
                float v = redS[b * 132 + c2] + redS[4224 + b * 132 + c2]
                        + redS[8448 + b * 132 + c2] + redS[12672 + b * 132 + c2]
                        + fc_b[bid * 128 + c2];
                out_t[(size_t)b * V_ + bid * 128 + c2] = v;
                redS[b * 132 + c2] = v;
            }
            __syncthreads();
            {
                const int b = tid & 31, ch = tid >> 5;
                float bv = -INFINITY; int bi = 0;
#pragma unroll
                for (int j = 0; j < 16; ++j) {
                    const int c2 = (ch << 4) + j;
                    const float v = redS[b * 132 + c2];
                    if (v > bv) { bv = v; bi = c2; }
                }
                rv[tid] = bv; ri[tid] = bi;
            }
            __syncthreads();
            if (tid < B_) {
                float bv = -INFINITY; int bi = 0;
#pragma unroll
                for (int ch = 0; ch < 8; ++ch) {
                    const float v = rv[ch * 32 + tid];
                    if (v > bv) { bv = v; bi = ri[ch * 32 + tid]; }
                }
                pval[tid * NBL + bid] = bv;
                pidx[tid * NBL + bid] = bid * 128 + bi;
            }
        }
        gridbar(bar + 2 * t - 1);
    }
}

// ---------------------------------------------------------------------------
extern "C" void kernel_launch(void* const* d_in, const int* in_sizes, int n_in,
                              void* d_out, int out_size, void* d_ws, size_t ws_size,
                              hipStream_t stream)
{
    (void)in_sizes; (void)n_in; (void)out_size; (void)ws_size;
    const int*   node_feat = (const int*)  d_in[0];
    const int*   mask      = (const int*)  d_in[1];
    const float* emb       = (const float*)d_in[2];
    const float* W_iou     = (const float*)d_in[3];
    const float* U_iou     = (const float*)d_in[4];
    const float* b_iou     = (const float*)d_in[5];
    const float* U_f_w     = (const float*)d_in[6];
    const float* U_f_b     = (const float*)d_in[7];
    const float* hid_fc_w  = (const float*)d_in[8];
    const float* hid_fc_b  = (const float*)d_in[9];
    const float* cell_fc_w = (const float*)d_in[10];
    const float* cell_fc_b = (const float*)d_in[11];
    const float* W_ih      = (const float*)d_in[12];
    const float* W_hh      = (const float*)d_in[13];
    const float* b_ih      = (const float*)d_in[14];
    const float* b_hh      = (const float*)d_in[15];
    const float* fc_w      = (const float*)d_in[16];
    const float* fc_b      = (const float*)d_in[17];
    float* out = (float*)d_out;

    float* ws      = (float*)d_ws;
    float* iou_buf = ws;                      // 12,582,912 (8192 x 1536)
    float* cagg    = ws + 12582912;           //  4,194,304
    float* hbuf    = ws + 16777216;           // 16,760,832
    float* cbuf    = ws + 33538048;           // 16,760,832
    float* mf      = ws + 50298880;           //     16,384
    float* hsb     = ws + 50315264;           //     32,768 (ping-pong)
    float* csb     = ws + 50348032;           //     16,384
    float* pval    = ws + 50364416;           //      8,000
    int*   pidx    = (int*)(ws + 50372416);   //      8,000
    // after the tree, iou_buf is dead -> reuse for mean partials + barriers
    float*    mpart = iou_buf;                        // 131,072
    unsigned* bar   = (unsigned*)(iou_buf + 131072);  //       128

    // ---- tree: leaves (2 chunks of 256 nodes) ----
    for (int chunk = 0; chunk < 2; ++chunk) {
        const int first = 511 + 256 * chunk;
        dim3 g(64, 12);
        iou_gemm_k<true><<<g, 256, 0, stream>>>(node_feat, mask, emb, W_iou, U_iou,
                                                hbuf, iou_buf, first, 256, 8);
        apply_node_k<true><<<4096, 256, 0, stream>>>(iou_buf, b_iou, cagg,
                                                     hbuf, cbuf, first, 256, 8);
    }
    // ---- tree: internal levels ----
    for (int d = 8; d >= 0; --d) {
        const int n = 1 << d, first = n - 1;
        if (n <= 64) {
            dim3 gf((64 * n + 63) / 64, 8);
            fagg_small_k<<<gf, 256, 0, stream>>>(hbuf, cbuf, U_f_w, U_f_b, cagg, first, n, d);
            dim3 gi((32 * n + 63) / 64, 24);
            iou_small_k<<<gi, 256, 0, stream>>>(node_feat, mask, emb, W_iou, U_iou,
                                                hbuf, iou_buf, first, n, d);
        } else {
            dim3 gf((64 * n + 127) / 128, 4);
            fagg_gemm_k<<<gf, 256, 0, stream>>>(hbuf, cbuf, U_f_w, U_f_b, cagg, first, n, d);
            dim3 gi((32 * n + 127) / 128, 12);
            iou_gemm_k<false><<<gi, 256, 0, stream>>>(node_feat, mask, emb, W_iou, U_iou,
                                                      hbuf, iou_buf, first, n, d);
        }
        apply_node_k<false><<<16 * n, 256, 0, stream>>>(iou_buf, b_iou, cagg,
                                                        hbuf, cbuf, first, n, d);
    }
    // ---- barriers reset (iou_buf now dead) ----
    hipMemsetAsync(bar, 0, 128 * sizeof(unsigned), stream);
    // ---- pool + init ----
    mean_part_k<<<256, 256, 0, stream>>>(hbuf, mpart);
    mean_fin_k<<<64, 256, 0, stream>>>(mpart, mf);
    hidcel_k<<<128, 256, 0, stream>>>(mf, hid_fc_w, hid_fc_b, cell_fc_w, cell_fc_b, hsb, csb);
    // ---- out[0] = 0 ----
    hipMemsetAsync(d_out, 0, (size_t)B_ * V_ * sizeof(float), stream);
    // ---- persistent decoder ----
    decoder_k<<<DECB, 256, 0, stream>>>(emb, W_ih, W_hh, b_ih, b_hh, fc_w, fc_b,
                                        hsb, csb, out, pval, pidx, bar);
}

// Round 5
// 6402.302 us; speedup vs baseline: 1.3737x; 1.3737x over previous
//
#include <hip/hip_runtime.h>
#include <math.h>

#define B_ 32
#define N_ 1023
#define E_ 256
#define H_ 512
#define V_ 32000
#define T_ 64
#define NBL 250   // logits col-tiles (128 cols each)

__device__ __forceinline__ float sigf(float x) { return 1.0f / (1.0f + expf(-x)); }

// ---------------------------------------------------------------------------
// Tree iou GEMM (large levels): 128x128 tile, 8x8 micro.
// ---------------------------------------------------------------------------
template<bool LEAF>
__global__ void __launch_bounds__(256)
iou_gemm_k(const int* __restrict__ node_feat, const int* __restrict__ mask,
           const float* __restrict__ emb, const float* __restrict__ Wiou,
           const float* __restrict__ Uiou, const float* __restrict__ hbuf,
           float* __restrict__ iou_out, int first, int n, int nshift)
{
    const int rows = B_ * n;
    const int K = LEAF ? E_ : (E_ + H_);
    const int rt = blockIdx.x, ct = blockIdx.y;
    const int tid = threadIdx.x;
    const int tr = tid >> 4, tc = tid & 15;

    __shared__ __align__(16) float As[8][136];
    __shared__ __align__(16) float Bs[8][136];

    float acc[8][8];
#pragma unroll
    for (int i = 0; i < 8; ++i)
#pragma unroll
        for (int j = 0; j < 8; ++j) acc[i][j] = 0.0f;

    const int lrow = tid >> 1;
    const int lkq  = (tid & 1) << 2;
    const int grow = rt * 128 + lrow;
    const bool rvalid = grow < rows;
    int tok = 0; float mval = 0.0f; int hoff1 = 0, hoff2 = 0;
    if (rvalid) {
        const int b = grow >> nshift, j = grow & (n - 1);
        const int node = first + j;
        tok  = node_feat[b * N_ + node];
        mval = (float)mask[b * N_ + node];
        if (!LEAF) {
            hoff1 = (b * N_ + 2 * node + 1) * H_;
            hoff2 = hoff1 + H_;
        }
    }
    const int bk   = tid >> 5;
    const int bcol = (tid & 31) << 2;
    const int gcol = ct * 128 + bcol;

    const int nkt = K >> 3;
    for (int kt = 0; kt < nkt; ++kt) {
        const int k0 = kt << 3;
        {
            const int kg = k0 + lkq;
            float4 v = make_float4(0.f, 0.f, 0.f, 0.f);
            if (rvalid) {
                if (LEAF || kg < E_) {
                    float4 e = *(const float4*)(emb + tok * E_ + kg);
                    v.x = e.x * mval; v.y = e.y * mval; v.z = e.z * mval; v.w = e.w * mval;
                } else {
                    const int kk = kg - E_;
                    float4 h1 = *(const float4*)(hbuf + hoff1 + kk);
                    float4 h2 = *(const float4*)(hbuf + hoff2 + kk);
                    v.x = h1.x + h2.x; v.y = h1.y + h2.y;
                    v.z = h1.z + h2.z; v.w = h1.w + h2.w;
                }
            }
            As[lkq + 0][lrow] = v.x;
            As[lkq + 1][lrow] = v.y;
            As[lkq + 2][lrow] = v.z;
            As[lkq + 3][lrow] = v.w;
        }
        {
            const int kg = k0 + bk;
            const float* src = (LEAF || kg < E_) ? (Wiou + kg * 1536 + gcol)
                                                 : (Uiou + (kg - E_) * 1536 + gcol);
            *(float4*)&Bs[bk][bcol] = *(const float4*)src;
        }
        __syncthreads();
#pragma unroll
        for (int kk = 0; kk < 8; ++kk) {
            float a[8], bb[8];
            *(float4*)&a[0]  = *(const float4*)&As[kk][tr << 3];
            *(float4*)&a[4]  = *(const float4*)&As[kk][(tr << 3) + 4];
            *(float4*)&bb[0] = *(const float4*)&Bs[kk][tc << 2];
            *(float4*)&bb[4] = *(const float4*)&Bs[kk][(tc << 2) + 64];
#pragma unroll
            for (int i = 0; i < 8; ++i)
#pragma unroll
                for (int j = 0; j < 8; ++j)
                    acc[i][j] = fmaf(a[i], bb[j], acc[i][j]);
        }
        __syncthreads();
    }
#pragma unroll
    for (int i = 0; i < 8; ++i) {
        const int r = rt * 128 + (tr << 3) + i;
        if (r < rows) {
            float* dst = iou_out + (size_t)r * 1536 + ct * 128;
            *(float4*)(dst + (tc << 2))      = make_float4(acc[i][0], acc[i][1], acc[i][2], acc[i][3]);
            *(float4*)(dst + 64 + (tc << 2)) = make_float4(acc[i][4], acc[i][5], acc[i][6], acc[i][7]);
        }
    }
}

// ---------------------------------------------------------------------------
// Tree iou GEMM (small levels, n<=64): 64x64 tile, 4x4 micro. Internal only.
// ---------------------------------------------------------------------------
__global__ void __launch_bounds__(256)
iou_small_k(const int* __restrict__ node_feat, const int* __restrict__ mask,
            const float* __restrict__ emb, const float* __restrict__ Wiou,
            const float* __restrict__ Uiou, const float* __restrict__ hbuf,
            float* __restrict__ iou_out, int first, int n, int nshift)
{
    const int rows = B_ * n;
    const int rt = blockIdx.x, ct = blockIdx.y;   // ct: 24 tiles of 64 cols
    const int tid = threadIdx.x;
    const int tr = tid >> 4, tc = tid & 15;

    __shared__ __align__(16) float As[8][72];
    __shared__ __align__(16) float Bs[8][72];

    float acc[4][4];
#pragma unroll
    for (int i = 0; i < 4; ++i)
#pragma unroll
        for (int j = 0; j < 4; ++j) acc[i][j] = 0.0f;

    const int srow = tid & 63, skq = tid >> 6;
    const int grow = rt * 64 + srow;
    const bool rvalid = grow < rows;
    int tok = 0; float mval = 0.f; int hoff1 = 0, hoff2 = 0;
    if (rvalid) {
        const int b = grow >> nshift, j = grow & (n - 1);
        const int node = first + j;
        tok  = node_feat[b * N_ + node];
        mval = (float)mask[b * N_ + node];
        hoff1 = (b * N_ + 2 * node + 1) * H_;
        hoff2 = hoff1 + H_;
    }
    const int gcol = ct * 64 + srow;

    for (int kt = 0; kt < 96; ++kt) {
        const int k0 = kt << 3;
        {
            const int kg = k0 + (skq << 1);
            float2 v = make_float2(0.f, 0.f);
            if (rvalid) {
                if (kg < E_) {
                    float2 e = *(const float2*)(emb + tok * E_ + kg);
                    v.x = e.x * mval; v.y = e.y * mval;
                } else {
                    const int kk = kg - E_;
                    float2 h1 = *(const float2*)(hbuf + hoff1 + kk);
                    float2 h2 = *(const float2*)(hbuf + hoff2 + kk);
                    v.x = h1.x + h2.x; v.y = h1.y + h2.y;
                }
            }
            As[(skq << 1) + 0][srow] = v.x;
            As[(skq << 1) + 1][srow] = v.y;
        }
        {
            const int kg = k0 + (skq << 1);
            const float* s0 = (kg < E_) ? (Wiou + (size_t)kg * 1536 + gcol)
                                        : (Uiou + (size_t)(kg - E_) * 1536 + gcol);
            const float* s1 = ((kg + 1) < E_) ? (Wiou + (size_t)(kg + 1) * 1536 + gcol)
                                              : (Uiou + (size_t)(kg + 1 - E_) * 1536 + gcol);
            Bs[(skq << 1) + 0][srow] = *s0;
            Bs[(skq << 1) + 1][srow] = *s1;
        }
        __syncthreads();
#pragma unroll
        for (int kk = 0; kk < 8; ++kk) {
            float a[4], bb[4];
            *(float4*)&a[0]  = *(const float4*)&As[kk][tr << 2];
            *(float4*)&bb[0] = *(const float4*)&Bs[kk][tc << 2];
#pragma unroll
            for (int i = 0; i < 4; ++i)
#pragma unroll
                for (int j = 0; j < 4; ++j)
                    acc[i][j] = fmaf(a[i], bb[j], acc[i][j]);
        }
        __syncthreads();
    }
#pragma unroll
    for (int i = 0; i < 4; ++i) {
        const int r = rt * 64 + (tr << 2) + i;
        if (r < rows)
            *(float4*)(iou_out + (size_t)r * 1536 + ct * 64 + (tc << 2)) =
                make_float4(acc[i][0], acc[i][1], acc[i][2], acc[i][3]);
    }
}

// ---------------------------------------------------------------------------
// f-gate GEMM (large levels): 128x128 tile with fused c_agg epilogue.
// ---------------------------------------------------------------------------
__global__ void __launch_bounds__(256)
fagg_gemm_k(const float* __restrict__ hbuf, const float* __restrict__ cbuf,
            const float* __restrict__ Ufw, const float* __restrict__ Ufb,
            float* __restrict__ cagg, int first, int n, int nshift)
{
    const int rows = 64 * n;
    const int rt = blockIdx.x, ct = blockIdx.y;
    const int tid = threadIdx.x;
    const int tr = tid >> 4, tc = tid & 15;

    __shared__ __align__(16) float As[8][136];
    __shared__ __align__(16) float Bs[8][136];

    float acc[8][8];
#pragma unroll
    for (int i = 0; i < 8; ++i)
#pragma unroll
        for (int j = 0; j < 8; ++j) acc[i][j] = 0.0f;

    const int lrow = tid >> 1;
    const int lkq  = (tid & 1) << 2;
    const int grow = rt * 128 + lrow;
    const bool rvalid = grow < rows;
    int hoff = 0;
    if (rvalid) {
        const int bj = grow >> 1, s = grow & 1;
        const int b = bj >> nshift, j = bj & (n - 1);
        const int node = first + j;
        hoff = (b * N_ + 2 * node + 1 + s) * H_;
    }
    const int bk   = tid >> 5;
    const int bcol = (tid & 31) << 2;
    const int gcol = ct * 128 + bcol;

    for (int kt = 0; kt < 64; ++kt) {
        const int k0 = kt << 3;
        {
            const int kg = k0 + lkq;
            float4 v = make_float4(0.f, 0.f, 0.f, 0.f);
            if (rvalid) v = *(const float4*)(hbuf + hoff + kg);
            As[lkq + 0][lrow] = v.x;
            As[lkq + 1][lrow] = v.y;
            As[lkq + 2][lrow] = v.z;
            As[lkq + 3][lrow] = v.w;
        }
        {
            const int kg = k0 + bk;
            *(float4*)&Bs[bk][bcol] = *(const float4*)(Ufw + kg * H_ + gcol);
        }
        __syncthreads();
#pragma unroll
        for (int kk = 0; kk < 8; ++kk) {
            float a[8], bb[8];
            *(float4*)&a[0]  = *(const float4*)&As[kk][tr << 3];
            *(float4*)&a[4]  = *(const float4*)&As[kk][(tr << 3) + 4];
            *(float4*)&bb[0] = *(const float4*)&Bs[kk][tc << 2];
            *(float4*)&bb[4] = *(const float4*)&Bs[kk][(tc << 2) + 64];
#pragma unroll
            for (int i = 0; i < 8; ++i)
#pragma unroll
                for (int j = 0; j < 8; ++j)
                    acc[i][j] = fmaf(a[i], bb[j], acc[i][j]);
        }
        __syncthreads();
    }
#pragma unroll
    for (int p = 0; p < 4; ++p) {
        const int r0 = rt * 128 + (tr << 3) + 2 * p;
        if (r0 < rows) {
            const int bj = r0 >> 1;
            const int b = bj >> nshift, j = bj & (n - 1);
            const int node = first + j;
            const float* c1 = cbuf + (b * N_ + 2 * node + 1) * H_ + ct * 128;
            const float* c2 = c1 + H_;
            float* dst = cagg + bj * H_ + ct * 128;
#pragma unroll
            for (int g = 0; g < 2; ++g) {
                const int off = (g ? 64 : 0) + (tc << 2);
                const int jb = g * 4;
                float4 cc1 = *(const float4*)(c1 + off);
                float4 cc2 = *(const float4*)(c2 + off);
                float4 bbv = *(const float4*)(Ufb + ct * 128 + off);
                float4 res;
                res.x = sigf(acc[2*p][jb+0] + bbv.x) * cc1.x + sigf(acc[2*p+1][jb+0] + bbv.x) * cc2.x;
                res.y = sigf(acc[2*p][jb+1] + bbv.y) * cc1.y + sigf(acc[2*p+1][jb+1] + bbv.y) * cc2.y;
                res.z = sigf(acc[2*p][jb+2] + bbv.z) * cc1.z + sigf(acc[2*p+1][jb+2] + bbv.z) * cc2.z;
                res.w = sigf(acc[2*p][jb+3] + bbv.w) * cc1.w + sigf(acc[2*p+1][jb+3] + bbv.w) * cc2.w;
                *(float4*)(dst + off) = res;
            }
        }
    }
}

// ---------------------------------------------------------------------------
// f-gate GEMM (small levels, n<=64): 64x64 tile, 4x4 micro, fused epilogue.
// ---------------------------------------------------------------------------
__global__ void __launch_bounds__(256)
fagg_small_k(const float* __restrict__ hbuf, const float* __restrict__ cbuf,
             const float* __restrict__ Ufw, const float* __restrict__ Ufb,
             float* __restrict__ cagg, int first, int n, int nshift)
{
    const int rows = 64 * n;
    const int rt = blockIdx.x, ct = blockIdx.y;   // ct: 8 tiles of 64 cols
    const int tid = threadIdx.x;
    const int tr = tid >> 4, tc = tid & 15;

    __shared__ __align__(16) float As[8][72];
    __shared__ __align__(16) float Bs[8][72];

    float acc[4][4];
#pragma unroll
    for (int i = 0; i < 4; ++i)
#pragma unroll
        for (int j = 0; j < 4; ++j) acc[i][j] = 0.0f;

    const int srow = tid & 63, skq = tid >> 6;
    const int grow = rt * 64 + srow;
    const bool rvalid = grow < rows;
    int hoff = 0;
    if (rvalid) {
        const int bj = grow >> 1, s = grow & 1;
        const int b = bj >> nshift, j = bj & (n - 1);
        const int node = first + j;
        hoff = (b * N_ + 2 * node + 1 + s) * H_;
    }
    const int gcol = ct * 64 + srow;

    for (int kt = 0; kt < 64; ++kt) {
        const int k0 = kt << 3;
        {
            const int kg = k0 + (skq << 1);
            float2 v = make_float2(0.f, 0.f);
            if (rvalid) v = *(const float2*)(hbuf + hoff + kg);
            As[(skq << 1) + 0][srow] = v.x;
            As[(skq << 1) + 1][srow] = v.y;
        }
        {
            const int kg = k0 + (skq << 1);
            Bs[(skq << 1) + 0][srow] = Ufw[(size_t)kg * H_ + gcol];
            Bs[(skq << 1) + 1][srow] = Ufw[(size_t)(kg + 1) * H_ + gcol];
        }
        __syncthreads();
#pragma unroll
        for (int kk = 0; kk < 8; ++kk) {
            float a[4], bb[4];
            *(float4*)&a[0]  = *(const float4*)&As[kk][tr << 2];
            *(float4*)&bb[0] = *(const float4*)&Bs[kk][tc << 2];
#pragma unroll
            for (int i = 0; i < 4; ++i)
#pragma unroll
                for (int j = 0; j < 4; ++j)
                    acc[i][j] = fmaf(a[i], bb[j], acc[i][j]);
        }
        __syncthreads();
    }
#pragma unroll
    for (int p = 0; p < 2; ++p) {
        const int r0 = rt * 64 + (tr << 2) + 2 * p;
        if (r0 < rows) {
            const int bj = r0 >> 1;
            const int b = bj >> nshift, j = bj & (n - 1);
            const int node = first + j;
            const float* c1 = cbuf + (b * N_ + 2 * node + 1) * H_ + ct * 64;
            const float* c2 = c1 + H_;
            float* dst = cagg + bj * H_ + ct * 64;
            const int off = tc << 2;
            float4 cc1 = *(const float4*)(c1 + off);
            float4 cc2 = *(const float4*)(c2 + off);
            float4 bbv = *(const float4*)(Ufb + ct * 64 + off);
            float4 res;
            res.x = sigf(acc[2*p][0] + bbv.x) * cc1.x + sigf(acc[2*p+1][0] + bbv.x) * cc2.x;
            res.y = sigf(acc[2*p][1] + bbv.y) * cc1.y + sigf(acc[2*p+1][1] + bbv.y) * cc2.y;
            res.z = sigf(acc[2*p][2] + bbv.z) * cc1.z + sigf(acc[2*p+1][2] + bbv.z) * cc2.z;
            res.w = sigf(acc[2*p][3] + bbv.w) * cc1.w + sigf(acc[2*p+1][3] + bbv.w) * cc2.w;
            *(float4*)(dst + off) = res;
        }
    }
}

// ---------------------------------------------------------------------------
template<bool LEAF>
__global__ void apply_node_k(const float* __restrict__ iou,
                             const float* __restrict__ b_iou,
                             const float* __restrict__ cagg,
                             float* __restrict__ hbuf, float* __restrict__ cbuf,
                             int first, int n, int nshift)
{
    const int gid = blockIdx.x * 256 + threadIdx.x;
    if (gid >= B_ * n * 128) return;
    const int r = gid >> 7, col = (gid & 127) << 2;
    const float* row = iou + (size_t)r * 1536;
    float4 iv = *(const float4*)(row + col);
    float4 ov = *(const float4*)(row + 512 + col);
    float4 uv = *(const float4*)(row + 1024 + col);
    float4 bi = *(const float4*)(b_iou + col);
    float4 bo = *(const float4*)(b_iou + 512 + col);
    float4 bu = *(const float4*)(b_iou + 1024 + col);
    float4 ca = make_float4(0.f, 0.f, 0.f, 0.f);
    if (!LEAF) ca = *(const float4*)(cagg + r * H_ + col);
    float4 cn, hn;
    cn.x = sigf(iv.x + bi.x) * tanhf(uv.x + bu.x) + ca.x;
    cn.y = sigf(iv.y + bi.y) * tanhf(uv.y + bu.y) + ca.y;
    cn.z = sigf(iv.z + bi.z) * tanhf(uv.z + bu.z) + ca.z;
    cn.w = sigf(iv.w + bi.w) * tanhf(uv.w + bu.w) + ca.w;
    hn.x = sigf(ov.x + bo.x) * tanhf(cn.x);
    hn.y = sigf(ov.y + bo.y) * tanhf(cn.y);
    hn.z = sigf(ov.z + bo.z) * tanhf(cn.z);
    hn.w = sigf(ov.w + bo.w) * tanhf(cn.w);
    const int b = r >> nshift, j = r & (n - 1);
    const int node = first + j;
    const size_t o = (size_t)(b * N_ + node) * H_ + col;
    *(float4*)(cbuf + o) = cn;
    *(float4*)(hbuf + o) = hn;
}

// ---------------------------------------------------------------------------
// two-stage mean over nodes
// ---------------------------------------------------------------------------
__global__ void mean_part_k(const float* __restrict__ hbuf, float* __restrict__ mpart)
{
    const int bid = blockIdx.x;               // 256 = 32 b x 8 chunks
    const int b = bid >> 3, chunk = bid & 7;
    const int tid = threadIdx.x;
    const int n0 = chunk * 128;
    const int n1 = (n0 + 128 < N_) ? (n0 + 128) : N_;
    float s0 = 0.f, s1 = 0.f;
    for (int nn = n0; nn < n1; ++nn) {
        const float* p = hbuf + (size_t)(b * N_ + nn) * H_;
        s0 += p[tid];
        s1 += p[tid + 256];
    }
    mpart[(bid << 9) + tid]       = s0;
    mpart[(bid << 9) + tid + 256] = s1;
}

__global__ void mean_fin_k(const float* __restrict__ mpart, float* __restrict__ mf)
{
    const int gid = blockIdx.x * 256 + threadIdx.x;   // 16384
    const int b = gid >> 9, k = gid & 511;
    float s = 0.f;
#pragma unroll
    for (int c = 0; c < 8; ++c) s += mpart[(((b << 3) + c) << 9) + k];
    mf[gid] = s * (1.0f / 1023.0f);
}

__global__ void hidcel_k(const float* __restrict__ mf,
                         const float* __restrict__ hw, const float* __restrict__ hb,
                         const float* __restrict__ cw, const float* __restrict__ cb,
                         float* __restrict__ hs0, float* __restrict__ cs)
{
    const int gid = blockIdx.x * 256 + threadIdx.x;   // 32768
    const int which = gid >> 14;
    const int b = (gid >> 9) & 31, l = gid & 511;
    const float* W = which ? cw : hw;
    float acc = which ? cb[l] : hb[l];
#pragma unroll 8
    for (int k = 0; k < H_; ++k) acc = fmaf(mf[b * H_ + k], W[k * H_ + l], acc);
    if (which) cs[b * H_ + l] = acc; else hs0[b * H_ + l] = acc;
}

// ---------------------------------------------------------------------------
// decoder LSTM step: 256 blocks x 2 l-cols; waves K-split; xh staged in LDS.
// ---------------------------------------------------------------------------
__global__ void __launch_bounds__(256)
lstm_step_k(const float* __restrict__ emb, const float* __restrict__ W_ih,
            const float* __restrict__ W_hh, const float* __restrict__ b_ih,
            const float* __restrict__ b_hh, const float* __restrict__ pval,
            const int* __restrict__ pidx, const float* __restrict__ hs_in,
            float* __restrict__ hs_out, float* __restrict__ cs, int t)
{
    __shared__ __align__(16) float xh[768 * 32];   // 98.3 KB; reused for partials
    __shared__ float rv[256];
    __shared__ int   ri[256];
    __shared__ int   tokS[B_];
    const int tid = threadIdx.x;

    if (t == 1) {
        if (tid < B_) tokS[tid] = 0;
    } else {
        const int b = tid & 31, ch = tid >> 5;
        float bv = -INFINITY; int bi2 = 0x7fffffff;
        for (int p = ch; p < NBL; p += 8) {
            const float v = pval[b * NBL + p];
            const int  ix = pidx[b * NBL + p];
            if (v > bv || (v == bv && ix < bi2)) { bv = v; bi2 = ix; }
        }
        rv[tid] = bv; ri[tid] = bi2;
        __syncthreads();
        if (tid < B_) {
            float Bv = -INFINITY; int Bi = 0x7fffffff;
#pragma unroll
            for (int c2 = 0; c2 < 8; ++c2) {
                const float v = rv[c2 * 32 + tid];
                const int  ix = ri[c2 * 32 + tid];
                if (v > Bv || (v == Bv && ix < Bi)) { Bv = v; Bi = ix; }
            }
            tokS[tid] = Bi;
        }
    }
    __syncthreads();

    for (int idx = tid; idx < B_ * E_; idx += 256) {
        const int b = idx >> 8, k = idx & 255;
        xh[k * 32 + b] = emb[tokS[b] * E_ + k];
    }
    for (int idx = tid; idx < B_ * H_; idx += 256) {
        const int b = idx >> 9, k = idx & 511;
        xh[(E_ + k) * 32 + b] = hs_in[b * H_ + k];
    }
    __syncthreads();

    const int b  = tid & 31;
    const int li = (tid >> 5) & 1;
    const int kq = tid >> 6;
    const int l  = blockIdx.x * 2 + li;
    float ai = 0.f, af = 0.f, ag = 0.f, ao = 0.f;
    {   // x part: rows [kq*64, kq*64+64)
        const float* w  = W_ih + (kq * 64) * 2048 + l;
        const float* xp = xh + (kq * 64) * 32 + b;
#pragma unroll 8
        for (int k = 0; k < 64; ++k) {
            const float x = xp[k * 32];
            ai = fmaf(x, w[0],    ai);
            af = fmaf(x, w[512],  af);
            ag = fmaf(x, w[1024], ag);
            ao = fmaf(x, w[1536], ao);
            w += 2048;
        }
    }
    {   // h part: rows [kq*128, kq*128+128)
        const float* w  = W_hh + (kq * 128) * 2048 + l;
        const float* xp = xh + (E_ + kq * 128) * 32 + b;
#pragma unroll 8
        for (int k = 0; k < 128; ++k) {
            const float x = xp[k * 32];
            ai = fmaf(x, w[0],    ai);
            af = fmaf(x, w[512],  af);
            ag = fmaf(x, w[1024], ag);
            ao = fmaf(x, w[1536], ao);
            w += 2048;
        }
    }
    __syncthreads();           // all xh reads done; reuse as partial buffer
    {
        const int slot = ((kq * 2 + li) * 32 + b) * 4;
        xh[slot + 0] = ai; xh[slot + 1] = af;
        xh[slot + 2] = ag; xh[slot + 3] = ao;
    }
    __syncthreads();
    if (tid < 64) {
        const int b2 = tid & 31, li2 = tid >> 5;
        const int l2 = blockIdx.x * 2 + li2;
        float s0 = 0.f, s1 = 0.f, s2 = 0.f, s3 = 0.f;
#pragma unroll
        for (int q = 0; q < 4; ++q) {
            const int sl = ((q * 2 + li2) * 32 + b2) * 4;
            s0 += xh[sl + 0]; s1 += xh[sl + 1];
            s2 += xh[sl + 2]; s3 += xh[sl + 3];
        }
        const float gi = s0 + b_ih[l2]        + b_hh[l2];
        const float gf = s1 + b_ih[512 + l2]  + b_hh[512 + l2];
        const float gg = s2 + b_ih[1024 + l2] + b_hh[1024 + l2];
        const float go = s3 + b_ih[1536 + l2] + b_hh[1536 + l2];
        const float co = cs[b2 * H_ + l2];
        const float cn = sigf(gf) * co + sigf(gi) * tanhf(gg);
        cs[b2 * H_ + l2] = cn;
        hs_out[b2 * H_ + l2] = sigf(go) * tanhf(cn);
    }
}

// ---------------------------------------------------------------------------
// logits partial: grid (250, 2) = (col-tile 128, K-half 256). Wave owns 8 b
// over the whole K-half -> no cross-wave reduce, acc[8][2], LDS 36.9 KB,
// ~4 blocks/CU. Partials to workspace: partial[kh][b][V].
// ---------------------------------------------------------------------------
__global__ void __launch_bounds__(256)
logits_part_k(const float* __restrict__ fc_w, const float* __restrict__ hs,
              float* __restrict__ partial)
{
    __shared__ __align__(16) float sm[256 * 36];   // 36,864 B
    const int tid = threadIdx.x;
    const int blk = blockIdx.x;       // col tile
    const int kh  = blockIdx.y;       // k half

    // stage hs[kh*256 + k][b]; b-fast lanes -> conflict-free LDS writes
    for (int idx = tid; idx < B_ * 256; idx += 256) {
        const int b = idx & 31, k = idx >> 5;
        sm[k * 36 + b] = hs[b * H_ + kh * 256 + k];
    }
    __syncthreads();

    const int w8   = (tid >> 6) << 3;       // wave's b-chunk base: 0,8,16,24
    const int lane = tid & 63;
    const int col  = (blk << 7) + (lane << 1);

    float acc[8][2];
#pragma unroll
    for (int i = 0; i < 8; ++i) { acc[i][0] = 0.f; acc[i][1] = 0.f; }

    const float* wp = fc_w + (size_t)(kh * 256) * V_ + col;
    const float* hp = sm + w8;
    float2 wreg[8];
#pragma unroll
    for (int j = 0; j < 8; ++j) wreg[j] = *(const float2*)(wp + (size_t)j * V_);
    for (int kb = 0; kb < 32; ++kb) {
        float2 wnxt[8];
        if (kb < 31) {
            const float* wq = wp + (size_t)((kb + 1) << 3) * V_;
#pragma unroll
            for (int j = 0; j < 8; ++j) wnxt[j] = *(const float2*)(wq + (size_t)j * V_);
        }
#pragma unroll
        for (int j = 0; j < 8; ++j) {
            const float* hq = hp + ((kb << 3) + j) * 36;   // wave-uniform broadcast
            float hv[8];
            *(float4*)&hv[0] = *(const float4*)(hq);
            *(float4*)&hv[4] = *(const float4*)(hq + 4);
#pragma unroll
            for (int i = 0; i < 8; ++i) {
                acc[i][0] = fmaf(hv[i], wreg[j].x, acc[i][0]);
                acc[i][1] = fmaf(hv[i], wreg[j].y, acc[i][1]);
            }
        }
        if (kb < 31) {
#pragma unroll
            for (int j = 0; j < 8; ++j) wreg[j] = wnxt[j];
        }
    }
#pragma unroll
    for (int i = 0; i < 8; ++i) {
        float* dst = partial + (size_t)(kh * B_ + w8 + i) * V_ + col;
        *(float2*)dst = make_float2(acc[i][0], acc[i][1]);
    }
}

// ---------------------------------------------------------------------------
// logits finalize: 250 blocks. partial[0]+partial[1]+bias -> out, block argmax.
// thread: (b = tid>>3, 16 cols); 8 threads/b reduce via LDS.
// ---------------------------------------------------------------------------
__global__ void __launch_bounds__(256)
logits_fin_k(const float* __restrict__ partial, const float* __restrict__ fc_b,
             float* __restrict__ out_t, float* __restrict__ pval,
             int* __restrict__ pidx)
{
    __shared__ float rv[256];
    __shared__ int   ri[256];
    const int tid = threadIdx.x, blk = blockIdx.x;
    const int b = tid >> 3, cg = (tid & 7) << 4;
    const int colbase = (blk << 7) + cg;

    const float* p0 = partial + (size_t)b * V_ + colbase;
    const float* p1 = partial + (size_t)(B_ + b) * V_ + colbase;
    const float* bp = fc_b + colbase;
    float* op = out_t + (size_t)b * V_ + colbase;

    float bv = -INFINITY; int bi = 0;
#pragma unroll
    for (int q = 0; q < 4; ++q) {
        float4 a = *(const float4*)(p0 + (q << 2));
        float4 c = *(const float4*)(p1 + (q << 2));
        float4 d = *(const float4*)(bp + (q << 2));
        float4 v;
        v.x = a.x + c.x + d.x; v.y = a.y + c.y + d.y;
        v.z = a.z + c.z + d.z; v.w = a.w + c.w + d.w;
        *(float4*)(op + (q << 2)) = v;
        const int c0 = cg + (q << 2);
        if (v.x > bv) { bv = v.x; bi = c0 + 0; }
        if (v.y > bv) { bv = v.y; bi = c0 + 1; }
        if (v.z > bv) { bv = v.z; bi = c0 + 2; }
        if (v.w > bv) { bv = v.w; bi = c0 + 3; }
    }
    rv[tid] = bv; ri[tid] = bi;
    __syncthreads();
    if (tid < B_) {
        float Bv = -INFINITY; int Bi = 0;
#pragma unroll
        for (int q = 0; q < 8; ++q) {
            const float v = rv[(tid << 3) + q];     // ascending col order
            if (v > Bv) { Bv = v; Bi = ri[(tid << 3) + q]; }
        }
        pval[tid * NBL + blk] = Bv;
        pidx[tid * NBL + blk] = (blk << 7) + Bi;
    }
}

// ---------------------------------------------------------------------------
extern "C" void kernel_launch(void* const* d_in, const int* in_sizes, int n_in,
                              void* d_out, int out_size, void* d_ws, size_t ws_size,
                              hipStream_t stream)
{
    (void)in_sizes; (void)n_in; (void)out_size; (void)ws_size;
    const int*   node_feat = (const int*)  d_in[0];
    const int*   mask      = (const int*)  d_in[1];
    const float* emb       = (const float*)d_in[2];
    const float* W_iou     = (const float*)d_in[3];
    const float* U_iou     = (const float*)d_in[4];
    const float* b_iou     = (const float*)d_in[5];
    const float* U_f_w     = (const float*)d_in[6];
    const float* U_f_b     = (const float*)d_in[7];
    const float* hid_fc_w  = (const float*)d_in[8];
    const float* hid_fc_b  = (const float*)d_in[9];
    const float* cell_fc_w = (const float*)d_in[10];
    const float* cell_fc_b = (const float*)d_in[11];
    const float* W_ih      = (const float*)d_in[12];
    const float* W_hh      = (const float*)d_in[13];
    const float* b_ih      = (const float*)d_in[14];
    const float* b_hh      = (const float*)d_in[15];
    const float* fc_w      = (const float*)d_in[16];
    const float* fc_b      = (const float*)d_in[17];
    float* out = (float*)d_out;

    float* ws      = (float*)d_ws;
    float* iou_buf = ws;                      // 12,582,912 (8192 x 1536)
    float* cagg    = ws + 12582912;           //  4,194,304
    float* hbuf    = ws + 16777216;           // 16,760,832
    float* cbuf    = ws + 33538048;           // 16,760,832
    float* mf      = ws + 50298880;           //     16,384
    float* hsb     = ws + 50315264;           //     32,768 (ping-pong)
    float* csb     = ws + 50348032;           //     16,384
    float* pval    = ws + 50364416;           //      8,000
    int*   pidx    = (int*)(ws + 50372416);   //      8,000
    // after the tree, iou_buf is dead -> reuse for mean partials + logits partials
    float* mpart   = iou_buf;                 //    131,072
    float* partial = iou_buf + 262144;        //  2,048,000 (2 x 32 x 32000)

    // ---- tree: leaves (2 chunks of 256 nodes) ----
    for (int chunk = 0; chunk < 2; ++chunk) {
        const int first = 511 + 256 * chunk;
        dim3 g(64, 12);
        iou_gemm_k<true><<<g, 256, 0, stream>>>(node_feat, mask, emb, W_iou, U_iou,
                                                hbuf, iou_buf, first, 256, 8);
        apply_node_k<true><<<4096, 256, 0, stream>>>(iou_buf, b_iou, cagg,
                                                     hbuf, cbuf, first, 256, 8);
    }
    // ---- tree: internal levels ----
    for (int d = 8; d >= 0; --d) {
        const int n = 1 << d, first = n - 1;
        if (n <= 64) {
            dim3 gf((64 * n + 63) / 64, 8);
            fagg_small_k<<<gf, 256, 0, stream>>>(hbuf, cbuf, U_f_w, U_f_b, cagg, first, n, d);
            dim3 gi((32 * n + 63) / 64, 24);
            iou_small_k<<<gi, 256, 0, stream>>>(node_feat, mask, emb, W_iou, U_iou,
                                                hbuf, iou_buf, first, n, d);
        } else {
            dim3 gf((64 * n + 127) / 128, 4);
            fagg_gemm_k<<<gf, 256, 0, stream>>>(hbuf, cbuf, U_f_w, U_f_b, cagg, first, n, d);
            dim3 gi((32 * n + 127) / 128, 12);
            iou_gemm_k<false><<<gi, 256, 0, stream>>>(node_feat, mask, emb, W_iou, U_iou,
                                                      hbuf, iou_buf, first, n, d);
        }
        apply_node_k<false><<<16 * n, 256, 0, stream>>>(iou_buf, b_iou, cagg,
                                                        hbuf, cbuf, first, n, d);
    }
    // ---- pool + init ----
    mean_part_k<<<256, 256, 0, stream>>>(hbuf, mpart);
    mean_fin_k<<<64, 256, 0, stream>>>(mpart, mf);
    hidcel_k<<<128, 256, 0, stream>>>(mf, hid_fc_w, hid_fc_b, cell_fc_w, cell_fc_b, hsb, csb);
    // ---- out[0] = 0 ----
    hipMemsetAsync(d_out, 0, (size_t)B_ * V_ * sizeof(float), stream);
    // ---- decoder: 3 kernels per step ----
    for (int t = 1; t < T_; ++t) {
        const float* hs_in  = hsb + ((t - 1) & 1) * (B_ * H_);
        float*       hs_out = hsb + (t & 1) * (B_ * H_);
        lstm_step_k<<<256, 256, 0, stream>>>(emb, W_ih, W_hh, b_ih, b_hh,
                                             pval, pidx, hs_in, hs_out, csb, t);
        dim3 gl(NBL, 2);
        logits_part_k<<<gl, 256, 0, stream>>>(fc_w, hs_out, partial);
        logits_fin_k<<<NBL, 256, 0, stream>>>(partial, fc_b,
                                              out + (size_t)t * B_ * V_, pval, pidx);
    }
}